// Round 1
// baseline (496.295 us; speedup 1.0000x reference)
//
#include <hip/hip_runtime.h>
#include <hip/hip_bf16.h>

typedef __bf16 bf16_t;
typedef __bf16 bf16x8 __attribute__((ext_vector_type(8)));
typedef float f32x4 __attribute__((ext_vector_type(4)));

static constexpr int Mm = 3, Bb = 8, Ss = 512, Dd = 768;
static constexpr float NORMF = 0.036084391824351615f; // 1/sqrt(768)

#define BM 128
#define BN 128
#define BK 32
#define NT 256

enum { EPI_PROJ = 0, EPI_SCORES, EPI_CONF, EPI_BF16, EPI_F32 };

// Generic 128x128 tile MFMA GEMM: C[row,col] = epi( sum_k A[row,k]*Bt[col,k] ).
// A: [Mrows][K] (lda), Bt: [N][K] (ldb) -- both K-contiguous (NT form).
// 256 threads = 4 waves in 2x2; each wave owns a 64x64 sub-tile = 4x4 frags of 16x16.
// Fragment layouts per guide §3 (m89/m91 verified):
//   A/B frag: row/col = lane&15, k = (lane>>4)*8 + j  (one ds_read_b128)
//   C/D frag: col = lane&15, row = (lane>>4)*4 + reg
template<int EPI, bool AF32, bool BF32>
__device__ __forceinline__ void gemm_core(
    const void* __restrict__ Ap, const void* __restrict__ Bp,
    int lda, int ldb, int K,
    void* __restrict__ Cp, int ldc,
    const float* __restrict__ bias, float scale)
{
    __shared__ bf16_t As[BM][BK];   // 8 KiB
    __shared__ bf16_t Bs[BN][BK];   // 8 KiB

    const int tid  = threadIdx.x;
    const int lane = tid & 63;
    const int wv   = tid >> 6;
    const int wr   = wv >> 1, wc = wv & 1;
    const int lg   = lane >> 4, l16 = lane & 15;

    const int rowBase = blockIdx.y * BM;
    const int colBase = blockIdx.x * BN;

    f32x4 acc[4][4] = {};

    const int nk = K / BK;
    for (int kt = 0; kt < nk; ++kt) {
        __syncthreads();
        // stage A-tile [128][32] and B-tile [128][32] as bf16 (cvt if f32 source)
        #pragma unroll
        for (int it = 0; it < 2; ++it) {
            const int c  = tid + it * NT;       // 512 chunks of 8 per tile
            const int r  = c >> 2;
            const int k8 = (c & 3) * 8;
            const int gk = kt * BK + k8;
            bf16x8 v;
            if (AF32) {
                const float* s = (const float*)Ap + (size_t)(rowBase + r) * lda + gk;
                const f32x4 f0 = *(const f32x4*)s;
                const f32x4 f1 = *(const f32x4*)(s + 4);
                #pragma unroll
                for (int q = 0; q < 4; ++q) { v[q] = (bf16_t)f0[q]; v[q + 4] = (bf16_t)f1[q]; }
            } else {
                v = *(const bf16x8*)((const bf16_t*)Ap + (size_t)(rowBase + r) * lda + gk);
            }
            *(bf16x8*)&As[r][k8] = v;

            bf16x8 w;
            if (BF32) {
                const float* s = (const float*)Bp + (size_t)(colBase + r) * ldb + gk;
                const f32x4 f0 = *(const f32x4*)s;
                const f32x4 f1 = *(const f32x4*)(s + 4);
                #pragma unroll
                for (int q = 0; q < 4; ++q) { w[q] = (bf16_t)f0[q]; w[q + 4] = (bf16_t)f1[q]; }
            } else {
                w = *(const bf16x8*)((const bf16_t*)Bp + (size_t)(colBase + r) * ldb + gk);
            }
            *(bf16x8*)&Bs[r][k8] = w;
        }
        __syncthreads();

        bf16x8 af[4], bfr[4];
        #pragma unroll
        for (int m = 0; m < 4; ++m)
            af[m] = *(const bf16x8*)&As[wr * 64 + m * 16 + l16][lg * 8];
        #pragma unroll
        for (int n = 0; n < 4; ++n)
            bfr[n] = *(const bf16x8*)&Bs[wc * 64 + n * 16 + l16][lg * 8];
        #pragma unroll
        for (int m = 0; m < 4; ++m)
            #pragma unroll
            for (int n = 0; n < 4; ++n)
                acc[m][n] = __builtin_amdgcn_mfma_f32_16x16x32_bf16(af[m], bfr[n], acc[m][n], 0, 0, 0);
    }

    #pragma unroll
    for (int m = 0; m < 4; ++m) {
        #pragma unroll
        for (int n = 0; n < 4; ++n) {
            #pragma unroll
            for (int r = 0; r < 4; ++r) {
                const int row = rowBase + wr * 64 + m * 16 + lg * 4 + r;
                const int col = colBase + wc * 64 + n * 16 + l16;
                float v = acc[m][n][r];
                if (EPI == EPI_PROJ) {
                    v = fmaxf(v + bias[col], 0.f);
                    ((bf16_t*)Cp)[(size_t)row * ldc + col] = (bf16_t)v;
                } else if (EPI == EPI_SCORES) {
                    v = fmaxf(v * scale, 0.f);
                    ((float*)Cp)[(size_t)row * ldc + col] = v;
                } else if (EPI == EPI_CONF) {
                    v = v + bias[col];
                    v = 1.f / (1.f + expf(-v));
                    ((bf16_t*)Cp)[(size_t)row * ldc + col] = (bf16_t)v;
                } else if (EPI == EPI_BF16) {
                    ((bf16_t*)Cp)[(size_t)row * ldc + col] = (bf16_t)v;
                } else { // EPI_F32
                    ((float*)Cp)[(size_t)row * ldc + col] = v;
                }
            }
        }
    }
}

// ---- kernels -------------------------------------------------------------

__global__ __launch_bounds__(NT) void k_proj(const float* __restrict__ mod,
                                             const float* __restrict__ Wp,
                                             const float* __restrict__ bp,
                                             bf16_t* __restrict__ proj) {
    const int m = blockIdx.z;
    gemm_core<EPI_PROJ, true, true>(
        mod + (size_t)m * Bb * Ss * Dd, Wp + (size_t)m * Dd * Dd, Dd, Dd, Dd,
        proj + (size_t)m * Bb * Ss * Dd, Dd, bp + m * Dd, 1.f);
}

__global__ __launch_bounds__(NT) void k_scores(const bf16_t* __restrict__ proj,
                                               float* __restrict__ sf) {
    const int z = blockIdx.z;            // z = i*24 + j*8 + b
    const int i = z / 24, j = (z / 8) % 3, b = z % 8;
    gemm_core<EPI_SCORES, false, false>(
        proj + (size_t)(i * Bb + b) * Ss * Dd,
        proj + (size_t)(j * Bb + b) * Ss * Dd, Dd, Dd, Dd,
        sf + (size_t)z * Ss * Ss, Ss, nullptr, NORMF);
}

__global__ __launch_bounds__(NT) void k_conf(const bf16_t* __restrict__ proj,
                                             const bf16_t* __restrict__ wcbf,
                                             const float* __restrict__ bc,
                                             bf16_t* __restrict__ conf) {
    const int z = blockIdx.z;            // z = m*8 + b
    gemm_core<EPI_CONF, false, false>(
        proj + (size_t)z * Ss * Dd, wcbf, Dd, Dd, Dd,
        conf + (size_t)z * Ss * Ss, Ss, bc, 1.f);
}

__global__ __launch_bounds__(NT) void k_s2(const bf16_t* __restrict__ sb,
                                           const bf16_t* __restrict__ st,
                                           bf16_t* __restrict__ s2) {
    const size_t z = blockIdx.z, SS = (size_t)Ss * Ss;
    gemm_core<EPI_BF16, false, false>(
        sb + z * SS, st + z * SS, Ss, Ss, Ss, s2 + z * SS, Ss, nullptr, 1.f);
}

__global__ __launch_bounds__(NT) void k_out(const bf16_t* __restrict__ s2,
                                            const bf16_t* __restrict__ projT,
                                            float* __restrict__ outp) {
    const int z = blockIdx.z;            // z = i*24 + j*8 + b
    const int j = (z / 8) % 3, b = z % 8;
    gemm_core<EPI_F32, false, false>(
        s2 + (size_t)z * Ss * Ss,
        projT + (size_t)(j * Bb + b) * Dd * Ss, Ss, Ss, Ss,
        outp + (size_t)z * Ss * Dd, Dd, nullptr, 1.f);
}

// batched bf16 transpose: in[z][R][C] -> out[z][C][R], 64x64 tiles
__global__ __launch_bounds__(NT) void k_transpose(const bf16_t* __restrict__ in,
                                                  bf16_t* __restrict__ out,
                                                  int R, int C) {
    __shared__ bf16_t t[64][80];         // pad keeps 16B-aligned rows (160B stride)
    const size_t z = blockIdx.z;
    const bf16_t* ip = in + z * (size_t)R * C;
    bf16_t* op = out + z * (size_t)R * C;
    const int r0 = blockIdx.y * 64, c0 = blockIdx.x * 64;
    const int tid = threadIdx.x;
    #pragma unroll
    for (int it = 0; it < 2; ++it) {
        const int c = tid + it * NT;
        const int r = c >> 3, cc = (c & 7) * 8;
        *(bf16x8*)&t[r][cc] = *(const bf16x8*)(ip + (size_t)(r0 + r) * C + c0 + cc);
    }
    __syncthreads();
    #pragma unroll
    for (int it = 0; it < 2; ++it) {
        const int c = tid + it * NT;
        const int oc = c >> 3, rr = (c & 7) * 8;  // oc = input col = output row
        bf16x8 v;
        #pragma unroll
        for (int k = 0; k < 8; ++k) v[k] = t[rr + k][oc];
        *(bf16x8*)(op + (size_t)(c0 + oc) * R + r0 + rr) = v;
    }
}

// row softmax: one wave per row of 512 f32 -> bf16
__global__ __launch_bounds__(NT) void k_softmax(const float* __restrict__ sf,
                                                bf16_t* __restrict__ sb) {
    const int rowid = (blockIdx.x * NT + threadIdx.x) >> 6;
    const int lane = threadIdx.x & 63;
    const float* rp = sf + (size_t)rowid * Ss + lane * 8;
    const f32x4 a = *(const f32x4*)rp;
    const f32x4 b = *(const f32x4*)(rp + 4);
    float v[8];
    #pragma unroll
    for (int q = 0; q < 4; ++q) { v[q] = a[q]; v[q + 4] = b[q]; }
    float mx = v[0];
    #pragma unroll
    for (int q = 1; q < 8; ++q) mx = fmaxf(mx, v[q]);
    #pragma unroll
    for (int off = 1; off < 64; off <<= 1) mx = fmaxf(mx, __shfl_xor(mx, off, 64));
    float e[8], s = 0.f;
    #pragma unroll
    for (int q = 0; q < 8; ++q) { e[q] = expf(v[q] - mx); s += e[q]; }
    #pragma unroll
    for (int off = 1; off < 64; off <<= 1) s += __shfl_xor(s, off, 64);
    const float inv = 1.f / s;
    bf16x8 o;
    #pragma unroll
    for (int q = 0; q < 8; ++q) o[q] = (bf16_t)(e[q] * inv);
    *(bf16x8*)(sb + (size_t)rowid * Ss + lane * 8) = o;
}

__global__ void k_init(const float* __restrict__ Wc, bf16_t* __restrict__ wcbf,
                       float* __restrict__ out0) {
    const int i = blockIdx.x * NT + threadIdx.x;
    if (i == 0) out0[0] = 0.f;
    if (i < Ss * Dd) wcbf[i] = (bf16_t)Wc[i];
}

__global__ __launch_bounds__(NT) void k_loss(const bf16_t* __restrict__ sb,
                                             const bf16_t* __restrict__ conf,
                                             float* __restrict__ out0) {
    const size_t NE = (size_t)Mm * Bb * Ss * Ss;       // 6,291,456 (j,b,s,t)
    const size_t NCH = NE / 8;
    float local = 0.f;
    for (size_t c = blockIdx.x * (size_t)NT + threadIdx.x; c < NCH;
         c += gridDim.x * (size_t)NT) {
        const size_t base = c * 8;
        const bf16x8 s0 = *(const bf16x8*)(sb + base);
        const bf16x8 s1 = *(const bf16x8*)(sb + base + NE);
        const bf16x8 s2 = *(const bf16x8*)(sb + base + 2 * NE);
        const bf16x8 cf = *(const bf16x8*)(conf + base);
        #pragma unroll
        for (int k = 0; k < 8; ++k) {
            const float d = (float)s0[k] + (float)s1[k] + (float)s2[k] - (float)cf[k];
            local += d * d;
        }
    }
    #pragma unroll
    for (int off = 1; off < 64; off <<= 1) local += __shfl_xor(local, off, 64);
    __shared__ float wsum[4];
    if ((threadIdx.x & 63) == 0) wsum[threadIdx.x >> 6] = local;
    __syncthreads();
    if (threadIdx.x == 0) {
        const float s = wsum[0] + wsum[1] + wsum[2] + wsum[3];
        atomicAdd(out0, s * (1.0f / (float)NE));
    }
}

// ---- launch --------------------------------------------------------------

extern "C" void kernel_launch(void* const* d_in, const int* in_sizes, int n_in,
                              void* d_out, int out_size, void* d_ws, size_t ws_size,
                              hipStream_t stream) {
    const float* modality = (const float*)d_in[0];
    const float* Wp = (const float*)d_in[1];
    const float* bp = (const float*)d_in[2];
    const float* Wc = (const float*)d_in[3];
    const float* bc = (const float*)d_in[4];
    float* out = (float*)d_out;          // [0]=loss, [1..]=out flat [i,j,b,s,d]

    // ws layout (bytes); scores_f32 region reused by conf+S2 after softmax.
    char* ws = (char*)d_ws;
    bf16_t* proj  = (bf16_t*)(ws + 0);                       // 18,874,368
    bf16_t* projT = (bf16_t*)(ws + 18874368);                // 18,874,368
    bf16_t* wcbf  = (bf16_t*)(ws + 37748736);                //    786,432
    bf16_t* sb    = (bf16_t*)(ws + 38535168);                // 37,748,736 (softmax'd scores bf16)
    bf16_t* st    = (bf16_t*)(ws + 76283904);                // 37,748,736 (scores^T)
    float*  sf    = (float*) (ws + 114032640);               // 75,497,472 (pre-softmax f32, dead after k_softmax)
    bf16_t* conf  = (bf16_t*)(ws + 114032640);               // 12,582,912 (aliases sf)
    bf16_t* s2    = (bf16_t*)(ws + 114032640 + 37748736);    // 37,748,736 (aliases sf)
    // total: 189,530,112 bytes

    k_init<<<dim3((Ss * Dd) / NT), NT, 0, stream>>>(Wc, wcbf, out);
    k_proj<<<dim3(Dd / BN, (Bb * Ss) / BM, Mm), NT, 0, stream>>>(modality, Wp, bp, proj);
    k_transpose<<<dim3(Dd / 64, Ss / 64, Mm * Bb), NT, 0, stream>>>(proj, projT, Ss, Dd);
    k_scores<<<dim3(Ss / BN, Ss / BM, Mm * Mm * Bb), NT, 0, stream>>>(proj, sf);
    k_softmax<<<dim3((Mm * Mm * Bb * Ss) / 4), NT, 0, stream>>>(sf, sb);
    k_transpose<<<dim3(Ss / 64, Ss / 64, Mm * Mm * Bb), NT, 0, stream>>>(sb, st, Ss, Ss);
    k_conf<<<dim3(Ss / BN, Ss / BM, Mm * Bb), NT, 0, stream>>>(proj, wcbf, bc, conf);
    k_s2<<<dim3(Ss / BN, Ss / BM, Mm * Mm * Bb), NT, 0, stream>>>(sb, st, s2);
    k_out<<<dim3(Dd / BN, Ss / BM, Mm * Mm * Bb), NT, 0, stream>>>(s2, projT, out + 1);
    k_loss<<<dim3(1024), NT, 0, stream>>>(sb, conf, out);
}

// Round 3
// 379.021 us; speedup vs baseline: 1.3094x; 1.3094x over previous
//
#include <hip/hip_runtime.h>
#include <hip/hip_bf16.h>

typedef __bf16 bf16_t;
typedef __bf16 bf16x8 __attribute__((ext_vector_type(8)));
typedef float f32x4 __attribute__((ext_vector_type(4)));

static constexpr int Mm = 3, Bb = 8, Ss = 512, Dd = 768;
static constexpr float NORMF = 0.036084391824351615f; // 1/sqrt(768)

#define BM 128
#define BN 128
#define BK 32
#define NT 256

enum { EPI_PROJ = 0, EPI_E, EPI_CONF, EPI_BF16, EPI_F32 };

// async global->LDS, 16B per lane. LDS dest is wave-uniform base + lane*16.
__device__ __forceinline__ void gload16(const void* g, void* l) {
#if defined(__has_builtin) && __has_builtin(__builtin_amdgcn_global_load_lds)
    __builtin_amdgcn_global_load_lds(
        (const __attribute__((address_space(1))) void*)g,
        (__attribute__((address_space(3))) void*)l, 16, 0, 0);
#else
    *(bf16x8*)l = *(const bf16x8*)g;   // fallback (sync)
#endif
}

// XCD-aware swizzle: consecutive blockIdx round-robin across 8 XCDs; remap so
// each XCD owns a contiguous chunk of work ids (same-z blocks share one L2).
template<int NXY, int NX>
__device__ __forceinline__ void decode_swz(int& bx, int& by, int& bz) {
    const int bid = blockIdx.x;
    const int q = gridDim.x >> 3;                 // nwg % 8 == 0 at all call sites
    const int wid = (bid & 7) * q + (bid >> 3);
    bz = wid / NXY;
    const int rem = wid - bz * NXY;
    by = rem / NX;
    bx = rem - by * NX;
}

// 128x128 tile MFMA GEMM, NT form: C[row,col] = epi( sum_k A[row,k]*Bt[col,k] ).
// 4 waves 2x2, each wave 64x64 = 4x4 frags of 16x16x32.
// A/B frag: row/col = lane&15, k = (lane>>4)*8+j ; C/D frag: col = lane&15, row = (lane>>4)*4+r.
template<int EPI, bool F32IN>
__device__ __forceinline__ void gemm_core(
    const void* __restrict__ Ap, const void* __restrict__ Bp,
    int lda, int ldb, int K,
    void* __restrict__ Cp, int ldc,
    const float* __restrict__ bias, float scale,
    int rowBase, int colBase)
{
    __shared__ bf16_t As[BM][BK];   // 8 KiB, linear in gload chunk order
    __shared__ bf16_t Bs[BN][BK];   // 8 KiB

    const int tid  = threadIdx.x;
    const int lane = tid & 63;
    const int wv   = tid >> 6;
    const int wr   = wv >> 1, wc = wv & 1;
    const int lg   = lane >> 4, l16 = lane & 15;

    f32x4 acc[4][4] = {};

    const int nk = K / BK;
    for (int kt = 0; kt < nk; ++kt) {
        __syncthreads();                       // prev iter's ds_reads done (drained by MFMA operand waits)
        const int gk = kt * BK;
        if (F32IN) {
            #pragma unroll
            for (int it = 0; it < 2; ++it) {
                const int c  = tid + it * NT;
                const int r  = c >> 2;
                const int k8 = (c & 3) * 8;
                const float* sa = (const float*)Ap + (size_t)(rowBase + r) * lda + gk + k8;
                const f32x4 a0 = *(const f32x4*)sa;
                const f32x4 a1 = *(const f32x4*)(sa + 4);
                bf16x8 v;
                #pragma unroll
                for (int q = 0; q < 4; ++q) { v[q] = (bf16_t)a0[q]; v[q + 4] = (bf16_t)a1[q]; }
                *(bf16x8*)&As[r][k8] = v;
                const float* sb = (const float*)Bp + (size_t)(colBase + r) * ldb + gk + k8;
                const f32x4 b0 = *(const f32x4*)sb;
                const f32x4 b1 = *(const f32x4*)(sb + 4);
                bf16x8 w;
                #pragma unroll
                for (int q = 0; q < 4; ++q) { w[q] = (bf16_t)b0[q]; w[q + 4] = (bf16_t)b1[q]; }
                *(bf16x8*)&Bs[r][k8] = w;
            }
        } else {
            #pragma unroll
            for (int it = 0; it < 2; ++it) {
                const int c  = tid + it * NT;
                const int r  = c >> 2;
                const int k8 = (c & 3) * 8;
                const bf16_t* ga = (const bf16_t*)Ap + (size_t)(rowBase + r) * lda + gk + k8;
                gload16(ga, (char*)As + (size_t)(wv * 64 + it * NT) * 16);
                const bf16_t* gb = (const bf16_t*)Bp + (size_t)(colBase + r) * ldb + gk + k8;
                gload16(gb, (char*)Bs + (size_t)(wv * 64 + it * NT) * 16);
            }
            // RACE FIX (R2->R3): explicitly drain the LDS-DMA writes before the
            // consume barrier; do not rely on the compiler's pre-barrier drain.
            asm volatile("s_waitcnt vmcnt(0)" ::: "memory");
            __builtin_amdgcn_sched_barrier(0);
        }
        __syncthreads();                       // tiles visible to all waves

        bf16x8 af[4], bfr[4];
        #pragma unroll
        for (int m = 0; m < 4; ++m)
            af[m] = *(const bf16x8*)&As[wr * 64 + m * 16 + l16][lg * 8];
        #pragma unroll
        for (int n = 0; n < 4; ++n)
            bfr[n] = *(const bf16x8*)&Bs[wc * 64 + n * 16 + l16][lg * 8];
        #pragma unroll
        for (int m = 0; m < 4; ++m)
            #pragma unroll
            for (int n = 0; n < 4; ++n)
                acc[m][n] = __builtin_amdgcn_mfma_f32_16x16x32_bf16(af[m], bfr[n], acc[m][n], 0, 0, 0);
    }

    #pragma unroll
    for (int m = 0; m < 4; ++m) {
        #pragma unroll
        for (int n = 0; n < 4; ++n) {
            #pragma unroll
            for (int r = 0; r < 4; ++r) {
                const int row = rowBase + wr * 64 + m * 16 + lg * 4 + r;
                const int col = colBase + wc * 64 + n * 16 + l16;
                float v = acc[m][n][r];
                if (EPI == EPI_PROJ) {
                    v = fmaxf(v + bias[col], 0.f);
                    ((bf16_t*)Cp)[(size_t)row * ldc + col] = (bf16_t)v;
                } else if (EPI == EPI_E) {
                    v = fmaxf(v * scale, 0.f);
                    ((bf16_t*)Cp)[(size_t)row * ldc + col] = (bf16_t)v;
                } else if (EPI == EPI_CONF) {
                    v = v + bias[col];
                    v = 1.f / (1.f + __expf(-v));
                    ((bf16_t*)Cp)[(size_t)row * ldc + col] = (bf16_t)v;
                } else if (EPI == EPI_BF16) {
                    ((bf16_t*)Cp)[(size_t)row * ldc + col] = (bf16_t)v;
                } else { // EPI_F32
                    ((float*)Cp)[(size_t)row * ldc + col] = v;
                }
            }
        }
    }
}

// ---- kernels -------------------------------------------------------------

__global__ __launch_bounds__(NT) void k_proj(const float* __restrict__ mod,
                                             const float* __restrict__ Wp,
                                             const float* __restrict__ bp,
                                             bf16_t* __restrict__ proj) {
    int bx, by, m;
    decode_swz<192, 6>(bx, by, m);             // 6 x 32 x 3
    gemm_core<EPI_PROJ, true>(
        mod + (size_t)m * Bb * Ss * Dd, Wp + (size_t)m * Dd * Dd, Dd, Dd, Dd,
        proj + (size_t)m * Bb * Ss * Dd, Dd, bp + m * Dd, 1.f,
        by * BM, bx * BN);
}

__global__ __launch_bounds__(NT) void k_scores(const bf16_t* __restrict__ proj,
                                               bf16_t* __restrict__ E) {
    int bx, by, z;
    decode_swz<16, 4>(bx, by, z);              // 4 x 4 x 72 ; z = i*24 + j*8 + b
    const int i = z / 24, j = (z / 8) % 3, b = z % 8;
    gemm_core<EPI_E, false>(
        proj + (size_t)(i * Bb + b) * Ss * Dd,
        proj + (size_t)(j * Bb + b) * Ss * Dd, Dd, Dd, Dd,
        E + (size_t)z * Ss * Ss, Ss, nullptr, NORMF,
        by * BM, bx * BN);
}

__global__ __launch_bounds__(NT) void k_conf(const bf16_t* __restrict__ proj,
                                             const bf16_t* __restrict__ wcbf,
                                             const float* __restrict__ bc,
                                             bf16_t* __restrict__ conf) {
    int bx, by, z;
    decode_swz<16, 4>(bx, by, z);              // 4 x 4 x 24
    gemm_core<EPI_CONF, false>(
        proj + (size_t)z * Ss * Dd, wcbf, Dd, Dd, Dd,
        conf + (size_t)z * Ss * Ss, Ss, bc, 1.f,
        by * BM, bx * BN);
}

__global__ __launch_bounds__(NT) void k_s2(const bf16_t* __restrict__ P,
                                           const bf16_t* __restrict__ Pt,
                                           bf16_t* __restrict__ s2) {
    int bx, by, z;
    decode_swz<16, 4>(bx, by, z);              // 4 x 4 x 72
    const size_t SS = (size_t)Ss * Ss;
    gemm_core<EPI_BF16, false>(
        P + (size_t)z * SS, Pt + (size_t)z * SS, Ss, Ss, Ss,
        s2 + (size_t)z * SS, Ss, nullptr, 1.f,
        by * BM, bx * BN);
}

__global__ __launch_bounds__(NT) void k_out(const bf16_t* __restrict__ s2,
                                            const bf16_t* __restrict__ projT,
                                            float* __restrict__ outp) {
    int bx, by, z;
    decode_swz<24, 6>(bx, by, z);              // 6 x 4 x 72
    const int j = (z / 8) % 3, b = z % 8;
    gemm_core<EPI_F32, false>(
        s2 + (size_t)z * Ss * Ss,
        projT + (size_t)(j * Bb + b) * Dd * Ss, Ss, Ss, Ss,
        outp + (size_t)z * Ss * Dd, Dd, nullptr, 1.f,
        by * BM, bx * BN);
}

// batched bf16 transpose: in[z][R][C] -> out[z][C][R], 64x64 tiles (projT only)
__global__ __launch_bounds__(NT) void k_transpose(const bf16_t* __restrict__ in,
                                                  bf16_t* __restrict__ out,
                                                  int R, int C) {
    __shared__ bf16_t t[64][80];
    const size_t z = blockIdx.z;
    const bf16_t* ip = in + z * (size_t)R * C;
    bf16_t* op = out + z * (size_t)R * C;
    const int r0 = blockIdx.y * 64, c0 = blockIdx.x * 64;
    const int tid = threadIdx.x;
    #pragma unroll
    for (int it = 0; it < 2; ++it) {
        const int c = tid + it * NT;
        const int r = c >> 3, cc = (c & 7) * 8;
        *(bf16x8*)&t[r][cc] = *(const bf16x8*)(ip + (size_t)(r0 + r) * C + c0 + cc);
    }
    __syncthreads();
    #pragma unroll
    for (int it = 0; it < 2; ++it) {
        const int c = tid + it * NT;
        const int oc = c >> 3, rr = (c & 7) * 8;
        bf16x8 v;
        #pragma unroll
        for (int k = 0; k < 8; ++k) v[k] = t[rr + k][oc];
        *(bf16x8*)(op + (size_t)(c0 + oc) * R + r0 + rr) = v;
    }
}

// fused row-softmax + dual write (P and P^T). One block = 64-row strip of one z.
// LDS stored with XOR swizzle on the 16B-chunk index so the column gather for
// P^T is bank-conflict-free: chunk' = chunk ^ (r&7) ^ ((r>>3)&7).
__device__ __forceinline__ int lidx(int r, int c) {
    int cb = (c >> 3) ^ (r & 7) ^ ((r >> 3) & 7);
    return r * 512 + cb * 8 + (c & 7);
}

__global__ __launch_bounds__(NT) void k_softmaxT(const bf16_t* __restrict__ E,
                                                 bf16_t* __restrict__ P,
                                                 bf16_t* __restrict__ Pt) {
    __shared__ bf16_t L[64 * 512];             // 64 KiB
    const int z = blockIdx.y, strip = blockIdx.x;
    const size_t SS = (size_t)Ss * Ss;
    const bf16_t* ep = E + (size_t)z * SS + (size_t)strip * 64 * Ss;
    const int tid = threadIdx.x, lane = tid & 63, wv = tid >> 6;

    #pragma unroll 4
    for (int rr = 0; rr < 16; ++rr) {
        const int r = wv * 16 + rr;
        const bf16x8 v8 = *(const bf16x8*)(ep + (size_t)r * Ss + lane * 8);
        float v[8];
        float mx = -1e30f;
        #pragma unroll
        for (int q = 0; q < 8; ++q) { v[q] = (float)v8[q]; mx = fmaxf(mx, v[q]); }
        #pragma unroll
        for (int off = 1; off < 64; off <<= 1) mx = fmaxf(mx, __shfl_xor(mx, off, 64));
        float e[8], s = 0.f;
        #pragma unroll
        for (int q = 0; q < 8; ++q) { e[q] = __expf(v[q] - mx); s += e[q]; }
        #pragma unroll
        for (int off = 1; off < 64; off <<= 1) s += __shfl_xor(s, off, 64);
        const float inv = 1.f / s;
        bf16x8 o;
        #pragma unroll
        for (int q = 0; q < 8; ++q) o[q] = (bf16_t)(e[q] * inv);
        *(bf16x8*)&L[lidx(r, lane * 8)] = o;
    }
    __syncthreads();

    // P rows (coalesced; LDS row is a chunk-permutation -> conflict-free)
    bf16_t* pp = P + (size_t)z * SS + (size_t)strip * 64 * Ss;
    #pragma unroll
    for (int k = 0; k < 16; ++k) {
        const int cc = tid + k * NT;
        const int r = cc >> 6, c8 = (cc & 63) * 8;
        *(bf16x8*)(pp + (size_t)r * Ss + c8) = *(const bf16x8*)&L[lidx(r, c8)];
    }
    // P^T tile: Pt[t][strip*64 + s]
    bf16_t* pt = Pt + (size_t)z * SS + strip * 64;
    #pragma unroll
    for (int k = 0; k < 16; ++k) {
        const int cc = tid + k * NT;
        const int t = cc >> 3, s8 = (cc & 7) * 8;
        bf16x8 o;
        #pragma unroll
        for (int q = 0; q < 8; ++q) o[q] = L[lidx(s8 + q, t)];
        *(bf16x8*)(pt + (size_t)t * Ss + s8) = o;
    }
}

__global__ void k_init(const float* __restrict__ Wc, bf16_t* __restrict__ wcbf,
                       float* __restrict__ out0) {
    const int i = blockIdx.x * NT + threadIdx.x;
    if (i == 0) out0[0] = 0.f;
    if (i < Ss * Dd) wcbf[i] = (bf16_t)Wc[i];
}

__global__ __launch_bounds__(NT) void k_loss(const bf16_t* __restrict__ P,
                                             const bf16_t* __restrict__ conf,
                                             float* __restrict__ out0) {
    const size_t NE = (size_t)Mm * Bb * Ss * Ss;       // stride of i in [i,j,b,s,t]
    const size_t NCH = NE / 8;
    float local = 0.f;
    for (size_t c = blockIdx.x * (size_t)NT + threadIdx.x; c < NCH;
         c += gridDim.x * (size_t)NT) {
        const size_t base = c * 8;
        const bf16x8 s0 = *(const bf16x8*)(P + base);
        const bf16x8 s1 = *(const bf16x8*)(P + base + NE);
        const bf16x8 s2 = *(const bf16x8*)(P + base + 2 * NE);
        const bf16x8 cf = *(const bf16x8*)(conf + base);
        #pragma unroll
        for (int k = 0; k < 8; ++k) {
            const float d = (float)s0[k] + (float)s1[k] + (float)s2[k] - (float)cf[k];
            local += d * d;
        }
    }
    #pragma unroll
    for (int off = 1; off < 64; off <<= 1) local += __shfl_xor(local, off, 64);
    __shared__ float wsum[4];
    if ((threadIdx.x & 63) == 0) wsum[threadIdx.x >> 6] = local;
    __syncthreads();
    if (threadIdx.x == 0) {
        const float s = wsum[0] + wsum[1] + wsum[2] + wsum[3];
        atomicAdd(out0, s * (1.0f / (float)NE));
    }
}

// ---- launch --------------------------------------------------------------

extern "C" void kernel_launch(void* const* d_in, const int* in_sizes, int n_in,
                              void* d_out, int out_size, void* d_ws, size_t ws_size,
                              hipStream_t stream) {
    const float* modality = (const float*)d_in[0];
    const float* Wp = (const float*)d_in[1];
    const float* bp = (const float*)d_in[2];
    const float* Wc = (const float*)d_in[3];
    const float* bc = (const float*)d_in[4];
    float* out = (float*)d_out;          // [0]=loss, [1..]=out flat [i,j,b,s,d]

    char* ws = (char*)d_ws;
    bf16_t* proj  = (bf16_t*)(ws + 0);                       // 18,874,368
    bf16_t* projT = (bf16_t*)(ws + 18874368);                // 18,874,368
    bf16_t* wcbf  = (bf16_t*)(ws + 37748736);                //    786,432
    bf16_t* P     = (bf16_t*)(ws + 38535168);                // 37,748,736
    bf16_t* Pt    = (bf16_t*)(ws + 76283904);                // 37,748,736
    bf16_t* E     = (bf16_t*)(ws + 114032640);               // 37,748,736 (dead after softmaxT)
    bf16_t* S2    = (bf16_t*)(ws + 114032640);               // aliases E
    bf16_t* conf  = (bf16_t*)(ws + 151781376);               // 12,582,912  (end 164,364,288)

    k_init<<<dim3((Ss * Dd) / NT), NT, 0, stream>>>(Wc, wcbf, out);
    k_proj<<<dim3(576), NT, 0, stream>>>(modality, Wp, bp, proj);
    k_transpose<<<dim3(Dd / 64, Ss / 64, Mm * Bb), NT, 0, stream>>>(proj, projT, Ss, Dd);
    k_scores<<<dim3(1152), NT, 0, stream>>>(proj, E);
    k_softmaxT<<<dim3(Ss / 64, Mm * Mm * Bb), NT, 0, stream>>>(E, P, Pt);
    k_conf<<<dim3(384), NT, 0, stream>>>(proj, wcbf, bc, conf);
    k_s2<<<dim3(1152), NT, 0, stream>>>(P, Pt, S2);
    k_out<<<dim3(1728), NT, 0, stream>>>(S2, projT, out + 1);
    k_loss<<<dim3(1024), NT, 0, stream>>>(P, conf, out);
}